// Round 4
// baseline (12.374 us; speedup 1.0000x reference)
//
#include <hip/hip_runtime.h>

// QuanvolutionFilter: 4-qubit RY+CNOT circuit on every 2x2 patch.
//
// Algebra:
//  - Layer-1 RY(w0q) fuses into encoding angles: RY(w)RY(x)|0> = RY(x+w)|0>.
//  - Only CNOT(0,1)/CNOT(2,3) -> blocks {0,1},{2,3} never entangle; state is a
//    product of two 4-amp blocks; z0=zA*Scd, z1=zB*Scd, z2=Sab*zC, z3=Sab*zD.
//  - All angles pre-scaled to revolutions; raw v_sin/v_cos via builtins.
// Memory: wave owns 128 consecutive patches -> every load (float2) and store
// (float4) instruction is a dense, fully-coalesced segment.

typedef float f32x4 __attribute__((ext_vector_type(4)));

constexpr float QINVPI = 0.07957747154594767f;   // 0.5 / (2*pi)

__device__ __forceinline__ void block2q(float revA, float revB,
                                        float cw0, float sw0,
                                        float cw1, float sw1,
                                        float& z_hi, float& z_lo, float& S) {
    float cA = __builtin_amdgcn_cosf(revA), sA = __builtin_amdgcn_sinf(revA);
    float cB = __builtin_amdgcn_cosf(revB), sB = __builtin_amdgcn_sinf(revB);
    // Outer product with CNOT(hi,lo) folded (row hi=1 swapped):
    float ab00 = cA * cB, ab01 = cA * sB;
    float ab10 = sA * sB, ab11 = sA * cB;
    // Layer-2 RY on hi qubit:
    float t00 = cw0 * ab00 - sw0 * ab10;
    float t10 = sw0 * ab00 + cw0 * ab10;
    float t01 = cw0 * ab01 - sw0 * ab11;
    float t11 = sw0 * ab01 + cw0 * ab11;
    // Layer-2 RY on lo qubit:
    float u00 = cw1 * t00 - sw1 * t01;
    float u01 = sw1 * t00 + cw1 * t01;
    float u10 = cw1 * t10 - sw1 * t11;
    float u11 = sw1 * t10 + cw1 * t11;
    // Final CNOT folded into prob indexing.
    float p00 = u00 * u00, p01 = u01 * u01;
    float p10 = u11 * u11, p11 = u10 * u10;
    float s0 = p00 + p01, s1 = p10 + p11;
    z_hi = s0 - s1;
    z_lo = (p00 - p01) + (p10 - p11);
    S    = s0 + s1;
}

__device__ __forceinline__ f32x4 patch_ev(float x0, float x1, float x2, float x3,
                                          const float* __restrict__ wls) {
    float zA, zB, Sab, zC, zD, Scd;
    block2q(fmaf(x0, QINVPI, wls[8]),  fmaf(x1, QINVPI, wls[9]),
            wls[0], wls[4], wls[1], wls[5], zA, zB, Sab);
    block2q(fmaf(x2, QINVPI, wls[10]), fmaf(x3, QINVPI, wls[11]),
            wls[2], wls[6], wls[3], wls[7], zC, zD, Scd);
    f32x4 r;
    r.x = zA * Scd; r.y = zB * Scd; r.z = Sab * zC; r.w = Sab * zD;
    return r;
}

__global__ __launch_bounds__(256) void quanv_kernel(
    const float* __restrict__ x,   // [64,1,256,256]
    const float* __restrict__ w,   // [2,4]
    float* __restrict__ out,       // [N,4] flat
    int nthreads)                  // npatch/2
{
    __shared__ float wls[12];      // c1[4], s1[4], h0rev[4]
    if (threadIdx.x < 4) {
        int q = threadIdx.x;
        float r1 = w[4 + q] * QINVPI;
        wls[q]     = __builtin_amdgcn_cosf(r1);
        wls[4 + q] = __builtin_amdgcn_sinf(r1);
        wls[8 + q] = w[q] * QINVPI;
    }
    __syncthreads();

    int t = blockIdx.x * blockDim.x + threadIdx.x;
    if (t >= nthreads) return;

    int lane  = t & 63;
    int pbase = (t >> 6) << 7;          // wave owns patches [pbase, pbase+128)
    int b     = pbase >> 14;            // image index (wave-uniform)
    int r     = (pbase >> 7) & 127;     // patch row   (wave-uniform)

    const float*  rowb = x + ((size_t)b << 16) + ((size_t)(2 * r) << 8);
    const float2* r0   = reinterpret_cast<const float2*>(rowb);
    const float2* r1v  = reinterpret_cast<const float2*>(rowb + 256);
    float2 a0 = r0[lane];          // patch pbase+lane,    image row 2r
    float2 a1 = r1v[lane];         //                      image row 2r+1
    float2 c0 = r0[lane + 64];     // patch pbase+64+lane, image row 2r
    float2 c1 = r1v[lane + 64];    //                      image row 2r+1

    f32x4 ev0 = patch_ev(a0.x, a0.y, a1.x, a1.y, wls);
    f32x4 ev1 = patch_ev(c0.x, c0.y, c1.x, c1.y, wls);

    f32x4* o = reinterpret_cast<f32x4*>(out);
    __builtin_nontemporal_store(ev0, &o[pbase + lane]);        // dense 1KB/instr
    __builtin_nontemporal_store(ev1, &o[pbase + lane + 64]);   // dense 1KB/instr
}

extern "C" void kernel_launch(void* const* d_in, const int* in_sizes, int n_in,
                              void* d_out, int out_size, void* d_ws, size_t ws_size,
                              hipStream_t stream) {
    const float* x = (const float*)d_in[0];
    const float* w = (const float*)d_in[1];
    float* out = (float*)d_out;
    int nthreads = out_size / 8;   // 524,288 threads, 2 patches each
    int threads = 256;
    int blocks = (nthreads + threads - 1) / threads;
    quanv_kernel<<<blocks, threads, 0, stream>>>(x, w, out, nthreads);
}

// Round 5
// 11.565 us; speedup vs baseline: 1.0700x; 1.0700x over previous
//
#include <hip/hip_runtime.h>

// QuanvolutionFilter: 4-qubit RY+CNOT circuit on every 2x2 patch.
//
// Algebra:
//  - Layer-1 RY(w0q) fuses into encoding angles: RY(w)RY(x)|0> = RY(x+w)|0>.
//  - Only CNOT(0,1)/CNOT(2,3) -> blocks {0,1},{2,3} never entangle; state is a
//    product of two 4-amp blocks; z0=zA*Scd, z1=zB*Scd, z2=Sab*zC, z3=Sab*zD.
//  - All angles pre-scaled to revolutions; raw v_sin/v_cos via builtins.
// Memory: wave owns 128 consecutive patches -> every load (float2) and store
// (float4) instruction is a dense, fully-coalesced segment. NO nontemporal:
// write-once output is absorbed by L2/L3 and flushed lazily after kernel end;
// nt stores forced synchronous HBM writes and cost ~1 us (R4 post-mortem).

typedef float f32x4 __attribute__((ext_vector_type(4)));

constexpr float QINVPI = 0.07957747154594767f;   // 0.5 / (2*pi)

__device__ __forceinline__ void block2q(float revA, float revB,
                                        float cw0, float sw0,
                                        float cw1, float sw1,
                                        float& z_hi, float& z_lo, float& S) {
    float cA = __builtin_amdgcn_cosf(revA), sA = __builtin_amdgcn_sinf(revA);
    float cB = __builtin_amdgcn_cosf(revB), sB = __builtin_amdgcn_sinf(revB);
    // Outer product with CNOT(hi,lo) folded (row hi=1 swapped):
    float ab00 = cA * cB, ab01 = cA * sB;
    float ab10 = sA * sB, ab11 = sA * cB;
    // Layer-2 RY on hi qubit:
    float t00 = cw0 * ab00 - sw0 * ab10;
    float t10 = sw0 * ab00 + cw0 * ab10;
    float t01 = cw0 * ab01 - sw0 * ab11;
    float t11 = sw0 * ab01 + cw0 * ab11;
    // Layer-2 RY on lo qubit:
    float u00 = cw1 * t00 - sw1 * t01;
    float u01 = sw1 * t00 + cw1 * t01;
    float u10 = cw1 * t10 - sw1 * t11;
    float u11 = sw1 * t10 + cw1 * t11;
    // Final CNOT folded into prob indexing.
    float p00 = u00 * u00, p01 = u01 * u01;
    float p10 = u11 * u11, p11 = u10 * u10;
    float s0 = p00 + p01, s1 = p10 + p11;
    z_hi = s0 - s1;
    z_lo = (p00 - p01) + (p10 - p11);
    S    = s0 + s1;
}

__device__ __forceinline__ f32x4 patch_ev(float x0, float x1, float x2, float x3,
                                          const float* __restrict__ wls) {
    float zA, zB, Sab, zC, zD, Scd;
    block2q(fmaf(x0, QINVPI, wls[8]),  fmaf(x1, QINVPI, wls[9]),
            wls[0], wls[4], wls[1], wls[5], zA, zB, Sab);
    block2q(fmaf(x2, QINVPI, wls[10]), fmaf(x3, QINVPI, wls[11]),
            wls[2], wls[6], wls[3], wls[7], zC, zD, Scd);
    f32x4 r;
    r.x = zA * Scd; r.y = zB * Scd; r.z = Sab * zC; r.w = Sab * zD;
    return r;
}

__global__ __launch_bounds__(256) void quanv_kernel(
    const float* __restrict__ x,   // [64,1,256,256]
    const float* __restrict__ w,   // [2,4]
    float* __restrict__ out,       // [N,4] flat
    int nthreads)                  // npatch/2
{
    __shared__ float wls[12];      // c1[4], s1[4], h0rev[4]
    if (threadIdx.x < 4) {
        int q = threadIdx.x;
        float r1 = w[4 + q] * QINVPI;
        wls[q]     = __builtin_amdgcn_cosf(r1);
        wls[4 + q] = __builtin_amdgcn_sinf(r1);
        wls[8 + q] = w[q] * QINVPI;
    }
    __syncthreads();

    int t = blockIdx.x * blockDim.x + threadIdx.x;
    if (t >= nthreads) return;

    int lane  = t & 63;
    int pbase = (t >> 6) << 7;          // wave owns patches [pbase, pbase+128)
    int b     = pbase >> 14;            // image index (wave-uniform)
    int r     = (pbase >> 7) & 127;     // patch row   (wave-uniform)

    const float*  rowb = x + ((size_t)b << 16) + ((size_t)(2 * r) << 8);
    const float2* r0   = reinterpret_cast<const float2*>(rowb);
    const float2* r1v  = reinterpret_cast<const float2*>(rowb + 256);
    float2 a0 = r0[lane];          // patch pbase+lane,    image row 2r
    float2 a1 = r1v[lane];         //                      image row 2r+1
    float2 c0 = r0[lane + 64];     // patch pbase+64+lane, image row 2r
    float2 c1 = r1v[lane + 64];    //                      image row 2r+1

    f32x4 ev0 = patch_ev(a0.x, a0.y, a1.x, a1.y, wls);
    f32x4 ev1 = patch_ev(c0.x, c0.y, c1.x, c1.y, wls);

    f32x4* o = reinterpret_cast<f32x4*>(out);
    o[pbase + lane]      = ev0;    // dense 1KB/instr
    o[pbase + lane + 64] = ev1;    // dense 1KB/instr
}

extern "C" void kernel_launch(void* const* d_in, const int* in_sizes, int n_in,
                              void* d_out, int out_size, void* d_ws, size_t ws_size,
                              hipStream_t stream) {
    const float* x = (const float*)d_in[0];
    const float* w = (const float*)d_in[1];
    float* out = (float*)d_out;
    int nthreads = out_size / 8;   // 524,288 threads, 2 patches each
    int threads = 256;
    int blocks = (nthreads + threads - 1) / threads;
    quanv_kernel<<<blocks, threads, 0, stream>>>(x, w, out, nthreads);
}

// Round 6
// 11.458 us; speedup vs baseline: 1.0799x; 1.0093x over previous
//
#include <hip/hip_runtime.h>

// QuanvolutionFilter: 4-qubit RY+CNOT circuit on every 2x2 patch.
//
// Algebra:
//  - Layer-1 RY(w0q) fuses into encoding angles: RY(w)RY(x)|0> = RY(x+w)|0>.
//  - Only CNOT(0,1)/CNOT(2,3) -> blocks {0,1},{2,3} never entangle; state is a
//    product of two 4-amp blocks; z0=zA*Scd, z1=zB*Scd, z2=Sab*zC, z3=Sab*zD.
//  - All angles pre-scaled to revolutions; raw v_sin/v_cos via builtins.
// Memory: wave owns 128 consecutive patches -> every load (float2) and store
// (float4) instruction is a dense, fully-coalesced segment. No nontemporal
// (R4: nt forced synchronous HBM writes, +0.9us). No LDS/barrier prologue
// (R6): w is wave-uniform -> s_load + per-thread trig on uniform values is
// cheaper than global-load + __syncthreads + 12 ds_reads per thread.

typedef float f32x4 __attribute__((ext_vector_type(4)));

constexpr float QINVPI = 0.07957747154594767f;   // 0.5 / (2*pi)

__device__ __forceinline__ void block2q(float revA, float revB,
                                        float cw0, float sw0,
                                        float cw1, float sw1,
                                        float& z_hi, float& z_lo, float& S) {
    float cA = __builtin_amdgcn_cosf(revA), sA = __builtin_amdgcn_sinf(revA);
    float cB = __builtin_amdgcn_cosf(revB), sB = __builtin_amdgcn_sinf(revB);
    // Outer product with CNOT(hi,lo) folded (row hi=1 swapped):
    float ab00 = cA * cB, ab01 = cA * sB;
    float ab10 = sA * sB, ab11 = sA * cB;
    // Layer-2 RY on hi qubit:
    float t00 = cw0 * ab00 - sw0 * ab10;
    float t10 = sw0 * ab00 + cw0 * ab10;
    float t01 = cw0 * ab01 - sw0 * ab11;
    float t11 = sw0 * ab01 + cw0 * ab11;
    // Layer-2 RY on lo qubit:
    float u00 = cw1 * t00 - sw1 * t01;
    float u01 = sw1 * t00 + cw1 * t01;
    float u10 = cw1 * t10 - sw1 * t11;
    float u11 = sw1 * t10 + cw1 * t11;
    // Final CNOT folded into prob indexing.
    float p00 = u00 * u00, p01 = u01 * u01;
    float p10 = u11 * u11, p11 = u10 * u10;
    float s0 = p00 + p01, s1 = p10 + p11;
    z_hi = s0 - s1;
    z_lo = (p00 - p01) + (p10 - p11);
    S    = s0 + s1;
}

__global__ __launch_bounds__(256) void quanv_kernel(
    const float* __restrict__ x,   // [64,1,256,256]
    const float* __restrict__ w,   // [2,4]
    float* __restrict__ out,       // [N,4] flat
    int nthreads)                  // npatch/2
{
    int t = blockIdx.x * blockDim.x + threadIdx.x;
    if (t >= nthreads) return;

    // Wave-uniform weight prep: w loads scalarize to s_load; trig on uniform
    // values costs ~84 cyc/wave, no barrier, no LDS.
    float h0rev0 = w[0] * QINVPI, h0rev1 = w[1] * QINVPI;
    float h0rev2 = w[2] * QINVPI, h0rev3 = w[3] * QINVPI;
    float r10 = w[4] * QINVPI, r11 = w[5] * QINVPI;
    float r12 = w[6] * QINVPI, r13 = w[7] * QINVPI;
    float c10 = __builtin_amdgcn_cosf(r10), s10 = __builtin_amdgcn_sinf(r10);
    float c11 = __builtin_amdgcn_cosf(r11), s11 = __builtin_amdgcn_sinf(r11);
    float c12 = __builtin_amdgcn_cosf(r12), s12 = __builtin_amdgcn_sinf(r12);
    float c13 = __builtin_amdgcn_cosf(r13), s13 = __builtin_amdgcn_sinf(r13);

    int lane  = t & 63;
    int pbase = (t >> 6) << 7;          // wave owns patches [pbase, pbase+128)
    int b     = pbase >> 14;            // image index (wave-uniform)
    int r     = (pbase >> 7) & 127;     // patch row   (wave-uniform)

    const float*  rowb = x + ((size_t)b << 16) + ((size_t)(2 * r) << 8);
    const float2* r0   = reinterpret_cast<const float2*>(rowb);
    const float2* r1v  = reinterpret_cast<const float2*>(rowb + 256);
    float2 a0 = r0[lane];          // patch pbase+lane,    image row 2r
    float2 a1 = r1v[lane];         //                      image row 2r+1
    float2 c0 = r0[lane + 64];     // patch pbase+64+lane, image row 2r
    float2 c1 = r1v[lane + 64];    //                      image row 2r+1

    float zA, zB, Sab, zC, zD, Scd;
    f32x4 ev0, ev1;
    block2q(fmaf(a0.x, QINVPI, h0rev0), fmaf(a0.y, QINVPI, h0rev1),
            c10, s10, c11, s11, zA, zB, Sab);
    block2q(fmaf(a1.x, QINVPI, h0rev2), fmaf(a1.y, QINVPI, h0rev3),
            c12, s12, c13, s13, zC, zD, Scd);
    ev0.x = zA * Scd; ev0.y = zB * Scd; ev0.z = Sab * zC; ev0.w = Sab * zD;

    block2q(fmaf(c0.x, QINVPI, h0rev0), fmaf(c0.y, QINVPI, h0rev1),
            c10, s10, c11, s11, zA, zB, Sab);
    block2q(fmaf(c1.x, QINVPI, h0rev2), fmaf(c1.y, QINVPI, h0rev3),
            c12, s12, c13, s13, zC, zD, Scd);
    ev1.x = zA * Scd; ev1.y = zB * Scd; ev1.z = Sab * zC; ev1.w = Sab * zD;

    f32x4* o = reinterpret_cast<f32x4*>(out);
    o[pbase + lane]      = ev0;    // dense 1KB/instr
    o[pbase + lane + 64] = ev1;    // dense 1KB/instr
}

extern "C" void kernel_launch(void* const* d_in, const int* in_sizes, int n_in,
                              void* d_out, int out_size, void* d_ws, size_t ws_size,
                              hipStream_t stream) {
    const float* x = (const float*)d_in[0];
    const float* w = (const float*)d_in[1];
    float* out = (float*)d_out;
    int nthreads = out_size / 8;   // 524,288 threads, 2 patches each
    int threads = 256;
    int blocks = (nthreads + threads - 1) / threads;
    quanv_kernel<<<blocks, threads, 0, stream>>>(x, w, out, nthreads);
}